// Round 1
// baseline (721.429 us; speedup 1.0000x reference)
//
#include <hip/hip_runtime.h>

typedef unsigned int u32;
typedef unsigned short u16;
typedef unsigned long long u64;

typedef __bf16 bf16x8 __attribute__((ext_vector_type(8)));
typedef float f32x4 __attribute__((ext_vector_type(4)));

#define DEV __device__ __forceinline__

// ---------- helpers ----------
DEV u16 f2bf(float f) {            // RNE float -> bf16
  u32 u = __float_as_uint(f);
  u += 0x7fffu + ((u >> 16) & 1u);
  return (u16)(u >> 16);
}
DEV float bflo(u32 u) { return __uint_as_float(u << 16); }
DEV float bfhi(u32 u) { return __uint_as_float(u & 0xffff0000u); }

DEV void unpack8(uint4 u, float* f) {
  f[0] = bflo(u.x); f[1] = bfhi(u.x);
  f[2] = bflo(u.y); f[3] = bfhi(u.y);
  f[4] = bflo(u.z); f[5] = bfhi(u.z);
  f[6] = bflo(u.w); f[7] = bfhi(u.w);
}

DEV void gld_lds16(const void* g, void* l) {
  // 16B/lane async global->LDS; LDS dst is wave-uniform base + lane*16
  __builtin_amdgcn_global_load_lds((const __attribute__((address_space(1))) u32*)g,
                                   (__attribute__((address_space(3))) u32*)l, 16, 0, 0);
}

// monotone (value, lower-index-wins) packed sort key
DEV u64 packkey(float f, u32 idx) {
  u32 u = __float_as_uint(f);
  u = (u & 0x80000000u) ? ~u : (u | 0x80000000u);
  return ((u64)u << 32) | (u32)(~idx);
}

// ---------- mask dtype sniffing (bool-as-u8 vs bool-as-i32) ----------
__global__ __launch_bounds__(64) void k_detect(const u32* m, int* flag) {
  if (threadIdx.x == 0) {
    int isInt = 1;
    for (int i = 0; i < 64; i++) if (m[i] > 1u) { isInt = 0; break; }
    *flag = isInt;   // 1: int32 words of 0/1, 0: packed bytes
  }
}

// ---------- hidden -> bf16 + column partial sums ----------
__global__ __launch_bounds__(256) void k_conv_mean(const float* __restrict__ hidden,
                                                   u16* __restrict__ hb,
                                                   float* __restrict__ partial) {
  const int col = blockIdx.x * 256 + threadIdx.x;   // 8 col-blocks
  const int r0 = blockIdx.y * 256;                  // 64 row-chunks
  float s = 0.f;
  for (int r = 0; r < 256; r++) {
    size_t off = (size_t)(r0 + r) * 2048 + col;
    float v = hidden[off];
    hb[off] = f2bf(v);
    s += v;
  }
  partial[blockIdx.y * 2048 + col] = s;
}

__global__ __launch_bounds__(256) void k_mean(const float* __restrict__ partial,
                                              float* __restrict__ mean) {
  const int col = blockIdx.x * 256 + threadIdx.x;
  float s = 0.f;
  for (int c = 0; c < 64; c++) s += partial[c * 2048 + col];
  mean[col] = s * (1.0f / 16384.0f);
}

// rough_query[d] = 0.25 * sum_h dot(Wq[h*256+d, :], mean)
__global__ __launch_bounds__(256) void k_rq(const float* __restrict__ Wq,
                                            const float* __restrict__ mean,
                                            float* __restrict__ rq) {
  const int gw = (blockIdx.x * 256 + threadIdx.x) >> 6;  // global wave 0..63
  const int l = threadIdx.x & 63;
  for (int row = gw; row < 1024; row += 64) {
    float s = 0.f;
    for (int j = 0; j < 32; j++)
      s = fmaf(Wq[(size_t)row * 2048 + j * 64 + l], mean[j * 64 + l], s);
    for (int mk = 1; mk < 64; mk <<= 1) s += __shfl_xor(s, mk);
    if (l == 0) atomicAdd(&rq[row & 255], 0.25f * s);
  }
}

// weights fp32 -> bf16 (2M elements each)
__global__ __launch_bounds__(256) void k_convw(const float* __restrict__ W,
                                               u16* __restrict__ Wb) {
  const int i = blockIdx.x * 256 + threadIdx.x;
  float4 v = ((const float4*)W)[i];
  ushort4 o; o.x = f2bf(v.x); o.y = f2bf(v.y); o.z = f2bf(v.z); o.w = f2bf(v.w);
  ((ushort4*)Wb)[i] = o;
}

// ---------- rough scores (one wave per belief) ----------
__global__ __launch_bounds__(256) void k_rough(const float* __restrict__ beliefs,
                                               const void* __restrict__ amask,
                                               const int* __restrict__ flag,
                                               const float* __restrict__ rq,
                                               u64* __restrict__ keys) {
  const int t = threadIdx.x, w = t >> 6, l = t & 63;
  const int n = blockIdx.x * 4 + w;
  float4 b = *(const float4*)(beliefs + (size_t)n * 256 + l * 4);
  float4 qv = *(const float4*)(rq + l * 4);
  float dot = b.x * qv.x + b.y * qv.y + b.z * qv.z + b.w * qv.w;
  float ss = b.x * b.x + b.y * b.y + b.z * b.z + b.w * b.w;
  for (int mk = 1; mk < 64; mk <<= 1) { dot += __shfl_xor(dot, mk); ss += __shfl_xor(ss, mk); }
  if (l == 0) {
    bool act = (*flag) ? (((const int*)amask)[n] != 0)
                       : (((const unsigned char*)amask)[n] != 0);
    float score = act ? dot / fmaxf(sqrtf(ss), 1e-8f) : -1e30f;
    keys[n] = packkey(score, (u32)n);
  }
}

// ---------- exact top-32, hierarchical argmax over packed keys ----------
__global__ __launch_bounds__(256) void k_topk(const u64* __restrict__ in, int cnt,
                                              u64* __restrict__ outk, int* __restrict__ outi) {
  __shared__ u64 buf[2048];
  __shared__ u64 wmaxS[4];
  const int t = threadIdx.x;
  const int slots = cnt >> 8;                 // 4 (stage1) or 8 (stage2)
  const u64* src = in + (size_t)blockIdx.x * cnt;
  for (int i = 0; i < slots; i++) buf[t + i * 256] = src[t + i * 256];
  __syncthreads();
  const int l = t & 63, w = t >> 6;
  for (int r = 0; r < 32; r++) {
    u64 m = 0;
    for (int i = 0; i < slots; i++) { u64 v = buf[t + i * 256]; m = v > m ? v : m; }
    for (int mk = 1; mk < 64; mk <<= 1) { u64 o = __shfl_xor(m, mk); m = o > m ? o : m; }
    if (l == 0) wmaxS[w] = m;
    __syncthreads();
    u64 a = wmaxS[0] > wmaxS[1] ? wmaxS[0] : wmaxS[1];
    u64 b = wmaxS[2] > wmaxS[3] ? wmaxS[2] : wmaxS[3];
    u64 win = a > b ? a : b;
    for (int i = 0; i < slots; i++) if (buf[t + i * 256] == win) buf[t + i * 256] = 0ull;
    if (t == 0) {
      if (outk) outk[blockIdx.x * 32 + r] = win;
      if (outi) outi[r] = (int)(~(u32)(win & 0xffffffffull));
    }
    __syncthreads();
  }
}

// ---------- gather + keys/values/goal-bias/temperature ----------
__global__ __launch_bounds__(256) void k_prep(const float* __restrict__ beliefs,
                                              const float* __restrict__ goals,
                                              const float* __restrict__ prio,
                                              const float* __restrict__ logt,
                                              const int* __restrict__ topk,
                                              u16* __restrict__ keysb, u16* __restrict__ valsb,
                                              float* __restrict__ biasO, float* __restrict__ tempO) {
  __shared__ float keysf[32 * 256];
  __shared__ float gradS[16];
  const int t = threadIdx.x, w = t >> 6, l = t & 63;
  for (int g = w * 4; g < w * 4 + 4; g++) {
    float4 v = *(const float4*)(goals + g * 256 + l * 4);
    float ss = v.x * v.x + v.y * v.y + v.z * v.z + v.w * v.w;
    for (int mk = 1; mk < 64; mk <<= 1) ss += __shfl_xor(ss, mk);
    if (l == 0) gradS[g] = fmaxf(sqrtf(ss), 1e-8f);
  }
  for (int kk = w * 8; kk < w * 8 + 8; kk++) {
    int idx = topk[kk];
    float4 v = *(const float4*)(beliefs + (size_t)idx * 256 + l * 4);
    float ss = v.x * v.x + v.y * v.y + v.z * v.z + v.w * v.w;
    for (int mk = 1; mk < 64; mk <<= 1) ss += __shfl_xor(ss, mk);
    float rr = 1.0f / fmaxf(sqrtf(ss), 1e-8f);
    float4 kv; kv.x = v.x * rr; kv.y = v.y * rr; kv.z = v.z * rr; kv.w = v.w * rr;
    *(float4*)&keysf[kk * 256 + l * 4] = kv;
    ushort4 kb; kb.x = f2bf(kv.x); kb.y = f2bf(kv.y); kb.z = f2bf(kv.z); kb.w = f2bf(kv.w);
    *(ushort4*)(keysb + kk * 256 + l * 4) = kb;
    ushort4 vb; vb.x = f2bf(v.x); vb.y = f2bf(v.y); vb.z = f2bf(v.z); vb.w = f2bf(v.w);
    *(ushort4*)(valsb + kk * 256 + l * 4) = vb;
  }
  __syncthreads();
  for (int kk = w * 8; kk < w * 8 + 8; kk++) {
    float4 kv = *(const float4*)&keysf[kk * 256 + l * 4];
    float best = -1e30f;
    for (int g = 0; g < 16; g++) {
      float4 gv = *(const float4*)(goals + g * 256 + l * 4);
      float d = kv.x * gv.x + kv.y * gv.y + kv.z * gv.z + kv.w * gv.w;
      for (int mk = 1; mk < 64; mk <<= 1) d += __shfl_xor(d, mk);
      float sim = d / gradS[g] * prio[g];
      best = fmaxf(best, sim);
    }
    if (l == 0) biasO[kk] = best;
  }
  if (t < 4) tempO[t] = fmaxf(__expf(logt[t]), 0.1f);
}

// ---------- m97-style 128x128 bf16 NT GEMM: C[m][n] = sum_k A[m][k]*B[n][k] ----------
template <typename OutT>
__global__ __launch_bounds__(256) void k_gemm_nt(const u16* __restrict__ A,
                                                 const u16* __restrict__ B,
                                                 OutT* __restrict__ C,
                                                 int M, int N, int K) {
  __shared__ __align__(16) u16 As[128 * 32];
  __shared__ __align__(16) u16 Bs[128 * 32];
  const int t = threadIdx.x;
  const int w = t >> 6, l = t & 63;
  const int m0 = blockIdx.y * 128, n0 = blockIdx.x * 128;
  const int wm = (w >> 1) * 64, wn = (w & 1) * 64;
  const int c = l & 15, q = l >> 4;
  f32x4 acc[4][4] = {};
  const int rsrc = w * 16 + (l >> 2);     // staging row within tile
  const int kc = (l & 3) * 8;             // staging k-offset (8 bf16 = 16B)
  const u16* Ab = A + (size_t)(m0 + rsrc) * K + kc;
  const u16* Bb = B + (size_t)(n0 + rsrc) * K + kc;
  u16* AsW = &As[w * 512];                // wave-uniform LDS bases
  u16* BsW = &Bs[w * 512];
  for (int kt = 0; kt < K; kt += 32) {
    gld_lds16(Ab + kt, AsW);
    gld_lds16(Ab + (size_t)64 * K + kt, AsW + 2048);
    gld_lds16(Bb + kt, BsW);
    gld_lds16(Bb + (size_t)64 * K + kt, BsW + 2048);
    __syncthreads();
    bf16x8 af[4], bfr[4];
#pragma unroll
    for (int i = 0; i < 4; i++)
      af[i] = __builtin_bit_cast(bf16x8, *(const uint4*)&As[(wm + i * 16 + c) * 32 + q * 8]);
#pragma unroll
    for (int i = 0; i < 4; i++)
      bfr[i] = __builtin_bit_cast(bf16x8, *(const uint4*)&Bs[(wn + i * 16 + c) * 32 + q * 8]);
#pragma unroll
    for (int mi = 0; mi < 4; mi++)
#pragma unroll
      for (int ni = 0; ni < 4; ni++)
        acc[mi][ni] = __builtin_amdgcn_mfma_f32_16x16x32_bf16(af[mi], bfr[ni], acc[mi][ni], 0, 0, 0);
    __syncthreads();
  }
#pragma unroll
  for (int mi = 0; mi < 4; mi++)
#pragma unroll
    for (int ni = 0; ni < 4; ni++)
#pragma unroll
      for (int r = 0; r < 4; r++) {
        int row = m0 + wm + mi * 16 + q * 4 + r;   // C/D: row=(lane>>4)*4+reg
        int col = n0 + wn + ni * 16 + c;           //      col=lane&15
        float v = acc[mi][ni][r];
        if constexpr (sizeof(OutT) == 2) C[(size_t)row * N + col] = (OutT)f2bf(v);
        else                             C[(size_t)row * N + col] = v;
      }
}

// ---------- attention: scores/softmax/PV, one (row,head) per half-wave ----------
__global__ __launch_bounds__(256) void k_attn(const u16* __restrict__ Qb,
                                              const u16* __restrict__ keysb,
                                              const u16* __restrict__ valsb,
                                              const float* __restrict__ biasg,
                                              const float* __restrict__ tempg,
                                              u16* __restrict__ R) {
  __shared__ uint4 Ks[32 * 32];   // 32 keys x 256 bf16
  __shared__ uint4 Vs[32 * 32];
  __shared__ float biasS[32];
  __shared__ float tempS[4];
  const int t = threadIdx.x;
  {
    const uint4* gk = (const uint4*)keysb;
    const uint4* gv = (const uint4*)valsb;
#pragma unroll
    for (int i = 0; i < 4; i++) { Ks[t + i * 256] = gk[t + i * 256]; Vs[t + i * 256] = gv[t + i * 256]; }
    if (t < 32) biasS[t] = biasg[t];
    if (t < 4) tempS[t] = tempg[t];
  }
  __syncthreads();
  const int l = t & 63, w = t >> 6;
  const int hw = l >> 5, sl = l & 31;
  const int pid = blockIdx.x * 8 + w * 2 + hw;   // (row,head) pair id
  const int row = pid >> 2, h = pid & 3;
  uint4 qw = *(const uint4*)(Qb + (size_t)row * 1024 + h * 256 + sl * 8);
  float qf[8]; unpack8(qw, qf);
  float acc[32];
#pragma unroll
  for (int n = 0; n < 32; n++) {
    float kf[8]; unpack8(Ks[n * 32 + sl], kf);
    float s = qf[0] * kf[0];
#pragma unroll
    for (int j = 1; j < 8; j++) s = fmaf(qf[j], kf[j], s);
    acc[n] = s;
  }
#pragma unroll
  for (int mk = 1; mk <= 16; mk <<= 1)
#pragma unroll
    for (int n = 0; n < 32; n++) acc[n] += __shfl_xor(acc[n], mk);
  const float scale = tempS[h] * 0.0625f;        // temp / sqrt(256)
  float mx = -1e30f;
#pragma unroll
  for (int n = 0; n < 32; n++) { acc[n] = fmaf(acc[n], scale, biasS[n]); mx = fmaxf(mx, acc[n]); }
  float sum = 0.f;
#pragma unroll
  for (int n = 0; n < 32; n++) { acc[n] = __expf(acc[n] - mx); sum += acc[n]; }
  const float inv = 1.0f / sum;
  float o[8] = {0, 0, 0, 0, 0, 0, 0, 0};
#pragma unroll
  for (int n = 0; n < 32; n++) {
    float vf[8]; unpack8(Vs[n * 32 + sl], vf);
#pragma unroll
    for (int j = 0; j < 8; j++) o[j] = fmaf(acc[n], vf[j], o[j]);
  }
  uint4 ow;
  ow.x = (u32)f2bf(o[0] * inv) | ((u32)f2bf(o[1] * inv) << 16);
  ow.y = (u32)f2bf(o[2] * inv) | ((u32)f2bf(o[3] * inv) << 16);
  ow.z = (u32)f2bf(o[4] * inv) | ((u32)f2bf(o[5] * inv) << 16);
  ow.w = (u32)f2bf(o[6] * inv) | ((u32)f2bf(o[7] * inv) << 16);
  *(uint4*)(R + (size_t)row * 1024 + h * 256 + sl * 8) = ow;
}

// ---------- launch ----------
extern "C" void kernel_launch(void* const* d_in, const int* in_sizes, int n_in,
                              void* d_out, int out_size, void* d_ws, size_t ws_size,
                              hipStream_t stream) {
  const float* hidden = (const float*)d_in[0];
  const float* beliefs = (const float*)d_in[1];
  const void* amask = d_in[2];
  const float* goals = (const float*)d_in[3];
  const float* prio = (const float*)d_in[4];
  const float* Wq = (const float*)d_in[5];
  const float* Wo = (const float*)d_in[6];
  const float* logt = (const float*)d_in[7];
  float* out = (float*)d_out;

  char* ws = (char*)d_ws;
  size_t off = 0;
  auto alloc = [&](size_t bytes) { char* p = ws + off; off = (off + bytes + 255) & ~(size_t)255; return p; };
  u16* hb      = (u16*)alloc(67108864);   // hidden bf16
  u16* wqb     = (u16*)alloc(4194304);
  u16* wob     = (u16*)alloc(4194304);
  u16* Qb      = (u16*)alloc(33554432);   // queries bf16
  u16* retr    = (u16*)alloc(33554432);   // retrieved bf16
  float* partial = (float*)alloc(524288);
  float* meanq = (float*)alloc(8192);
  float* rq    = (float*)alloc(1024);
  u64* keys    = (u64*)alloc(524288);
  u64* cands   = (u64*)alloc(16384);
  int* topkidx = (int*)alloc(128);
  u16* keysb   = (u16*)alloc(16384);
  u16* valsb   = (u16*)alloc(16384);
  float* biasv = (float*)alloc(128);
  float* tempv = (float*)alloc(16);
  int* flag    = (int*)alloc(16);

  hipMemsetAsync(rq, 0, 1024, stream);
  k_detect<<<1, 64, 0, stream>>>((const u32*)amask, flag);
  k_conv_mean<<<dim3(8, 64), 256, 0, stream>>>(hidden, hb, partial);
  k_mean<<<8, 256, 0, stream>>>(partial, meanq);
  k_rq<<<16, 256, 0, stream>>>(Wq, meanq, rq);
  k_convw<<<2048, 256, 0, stream>>>(Wq, wqb);
  k_convw<<<2048, 256, 0, stream>>>(Wo, wob);
  k_rough<<<16384, 256, 0, stream>>>(beliefs, amask, flag, rq, keys);
  k_topk<<<64, 256, 0, stream>>>(keys, 1024, cands, nullptr);
  k_topk<<<1, 256, 0, stream>>>(cands, 2048, nullptr, topkidx);
  k_prep<<<1, 256, 0, stream>>>(beliefs, goals, prio, logt, topkidx, keysb, valsb, biasv, tempv);
  k_gemm_nt<u16><<<dim3(8, 128), 256, 0, stream>>>(hb, wqb, Qb, 16384, 1024, 2048);
  k_attn<<<8192, 256, 0, stream>>>(Qb, keysb, valsb, biasv, tempv, retr);
  k_gemm_nt<float><<<dim3(16, 128), 256, 0, stream>>>(retr, wob, out, 16384, 2048, 1024);
}

// Round 2
// 553.213 us; speedup vs baseline: 1.3041x; 1.3041x over previous
//
#include <hip/hip_runtime.h>

typedef unsigned int u32;
typedef unsigned short u16;
typedef unsigned long long u64;

typedef __bf16 bf16x8 __attribute__((ext_vector_type(8)));
typedef float f32x4 __attribute__((ext_vector_type(4)));

#define DEV __device__ __forceinline__

// ---------- helpers ----------
DEV u16 f2bf(float f) {            // RNE float -> bf16
  u32 u = __float_as_uint(f);
  u += 0x7fffu + ((u >> 16) & 1u);
  return (u16)(u >> 16);
}

DEV void gld_lds16(const void* g, void* l) {
  __builtin_amdgcn_global_load_lds((const __attribute__((address_space(1))) u32*)g,
                                   (__attribute__((address_space(3))) u32*)l, 16, 0, 0);
}

// monotone (value, lower-index-wins) packed sort key
DEV u64 packkey(float f, u32 idx) {
  u32 u = __float_as_uint(f);
  u = (u & 0x80000000u) ? ~u : (u | 0x80000000u);
  return ((u64)u << 32) | (u32)(~idx);
}

// ---------- mask dtype sniffing (bool-as-u8 vs bool-as-i32) ----------
__global__ __launch_bounds__(64) void k_detect(const u32* m, int* flag) {
  u64 b = __ballot(m[threadIdx.x] > 1u);
  if (threadIdx.x == 0) *flag = (b == 0ull) ? 1 : 0;
}

// ---------- hidden -> bf16 + column partial sums (float4) ----------
__global__ __launch_bounds__(256) void k_conv_mean(const float4* __restrict__ hidden4,
                                                   ushort4* __restrict__ hb4,
                                                   float4* __restrict__ partial4) {
  const int c4 = blockIdx.x * 256 + threadIdx.x;   // 0..511
  const int r0 = blockIdx.y * 256;
  float4 s = {0.f, 0.f, 0.f, 0.f};
  for (int r = 0; r < 256; r++) {
    float4 v = hidden4[(size_t)(r0 + r) * 512 + c4];
    ushort4 o; o.x = f2bf(v.x); o.y = f2bf(v.y); o.z = f2bf(v.z); o.w = f2bf(v.w);
    hb4[(size_t)(r0 + r) * 512 + c4] = o;
    s.x += v.x; s.y += v.y; s.z += v.z; s.w += v.w;
  }
  partial4[blockIdx.y * 512 + c4] = s;
}

__global__ __launch_bounds__(256) void k_mean(const float* __restrict__ partial,
                                              float* __restrict__ mean) {
  const int col = blockIdx.x * 256 + threadIdx.x;
  float s = 0.f;
  for (int c = 0; c < 64; c++) s += partial[c * 2048 + col];
  mean[col] = s * (1.0f / 16384.0f);
}

// rough_query[d] = 0.25 * sum_h dot(Wq[h*256+d, :], mean)  — one wave per row
__global__ __launch_bounds__(256) void k_rq(const float* __restrict__ Wq,
                                            const float* __restrict__ mean,
                                            float* __restrict__ rq) {
  const int w = threadIdx.x >> 6, l = threadIdx.x & 63;
  const int row = blockIdx.x * 4 + w;      // 1024 rows
  float s = 0.f;
#pragma unroll
  for (int j = 0; j < 32; j++)
    s = fmaf(Wq[(size_t)row * 2048 + j * 64 + l], mean[j * 64 + l], s);
  for (int mk = 1; mk < 64; mk <<= 1) s += __shfl_xor(s, mk);
  if (l == 0) atomicAdd(&rq[row & 255], 0.25f * s);
}

// ---------- rough scores (one wave per belief) ----------
__global__ __launch_bounds__(256) void k_rough(const float* __restrict__ beliefs,
                                               const void* __restrict__ amask,
                                               const int* __restrict__ flag,
                                               const float* __restrict__ rq,
                                               u64* __restrict__ keys) {
  const int t = threadIdx.x, w = t >> 6, l = t & 63;
  const int n = blockIdx.x * 4 + w;
  float4 b = *(const float4*)(beliefs + (size_t)n * 256 + l * 4);
  float4 qv = *(const float4*)(rq + l * 4);
  float dot = b.x * qv.x + b.y * qv.y + b.z * qv.z + b.w * qv.w;
  float ss = b.x * b.x + b.y * b.y + b.z * b.z + b.w * b.w;
  for (int mk = 1; mk < 64; mk <<= 1) { dot += __shfl_xor(dot, mk); ss += __shfl_xor(ss, mk); }
  if (l == 0) {
    bool act = (*flag) ? (((const int*)amask)[n] != 0)
                       : (((const unsigned char*)amask)[n] != 0);
    float score = act ? dot / fmaxf(sqrtf(ss), 1e-8f) : -1e30f;
    keys[n] = packkey(score, (u32)n);
  }
}

// ---------- exact top-32, hierarchical argmax over packed keys ----------
__global__ __launch_bounds__(256) void k_topk(const u64* __restrict__ in, int cnt,
                                              u64* __restrict__ outk, int* __restrict__ outi) {
  __shared__ u64 buf[2048];
  __shared__ u64 wmaxS[4];
  const int t = threadIdx.x;
  const int slots = cnt >> 8;
  const u64* src = in + (size_t)blockIdx.x * cnt;
  for (int i = 0; i < slots; i++) buf[t + i * 256] = src[t + i * 256];
  __syncthreads();
  const int l = t & 63, w = t >> 6;
  for (int r = 0; r < 32; r++) {
    u64 m = 0;
    for (int i = 0; i < slots; i++) { u64 v = buf[t + i * 256]; m = v > m ? v : m; }
    for (int mk = 1; mk < 64; mk <<= 1) { u64 o = __shfl_xor(m, mk); m = o > m ? o : m; }
    if (l == 0) wmaxS[w] = m;
    __syncthreads();
    u64 a = wmaxS[0] > wmaxS[1] ? wmaxS[0] : wmaxS[1];
    u64 b = wmaxS[2] > wmaxS[3] ? wmaxS[2] : wmaxS[3];
    u64 win = a > b ? a : b;
    for (int i = 0; i < slots; i++) if (buf[t + i * 256] == win) buf[t + i * 256] = 0ull;
    if (t == 0) {
      if (outk) outk[blockIdx.x * 32 + r] = win;
      if (outi) outi[r] = (int)(~(u32)(win & 0xffffffffull));
    }
    __syncthreads();
  }
}

// ---------- gather + keys(f32)/values(f32)/goal-bias/temperature ----------
__global__ __launch_bounds__(256) void k_prep(const float* __restrict__ beliefs,
                                              const float* __restrict__ goals,
                                              const float* __restrict__ prio,
                                              const float* __restrict__ logt,
                                              const int* __restrict__ topk,
                                              float* __restrict__ keysf_g,
                                              float* __restrict__ valsf_g,
                                              float* __restrict__ biasO, float* __restrict__ tempO) {
  __shared__ float keysf[32 * 256];
  __shared__ float gradS[16];
  const int t = threadIdx.x, w = t >> 6, l = t & 63;
  for (int g = w * 4; g < w * 4 + 4; g++) {
    float4 v = *(const float4*)(goals + g * 256 + l * 4);
    float ss = v.x * v.x + v.y * v.y + v.z * v.z + v.w * v.w;
    for (int mk = 1; mk < 64; mk <<= 1) ss += __shfl_xor(ss, mk);
    if (l == 0) gradS[g] = fmaxf(sqrtf(ss), 1e-8f);
  }
  for (int kk = w * 8; kk < w * 8 + 8; kk++) {
    int idx = topk[kk];
    float4 v = *(const float4*)(beliefs + (size_t)idx * 256 + l * 4);
    float ss = v.x * v.x + v.y * v.y + v.z * v.z + v.w * v.w;
    for (int mk = 1; mk < 64; mk <<= 1) ss += __shfl_xor(ss, mk);
    float rr = 1.0f / fmaxf(sqrtf(ss), 1e-8f);
    float4 kv; kv.x = v.x * rr; kv.y = v.y * rr; kv.z = v.z * rr; kv.w = v.w * rr;
    *(float4*)&keysf[kk * 256 + l * 4] = kv;
    *(float4*)&keysf_g[kk * 256 + l * 4] = kv;
    *(float4*)&valsf_g[kk * 256 + l * 4] = v;
  }
  __syncthreads();
  for (int kk = w * 8; kk < w * 8 + 8; kk++) {
    float4 kv = *(const float4*)&keysf[kk * 256 + l * 4];
    float best = -1e30f;
    for (int g = 0; g < 16; g++) {
      float4 gv = *(const float4*)(goals + g * 256 + l * 4);
      float d = kv.x * gv.x + kv.y * gv.y + kv.z * gv.z + kv.w * gv.w;
      for (int mk = 1; mk < 64; mk <<= 1) d += __shfl_xor(d, mk);
      float sim = d / gradS[g] * prio[g];
      best = fmaxf(best, sim);
    }
    if (l == 0) biasO[kk] = best;
  }
  if (t < 4) tempO[t] = fmaxf(__expf(logt[t]), 0.1f);
}

// ---------- K' build: Kp[h*32+n, c] = sum_d keys[n,d] * Wq[h*256+d, c], bf16 out ----------
__global__ __launch_bounds__(256) void k_build_kp(const float* __restrict__ Wq,
                                                  const float* __restrict__ keysf_g,
                                                  u16* __restrict__ Kp) {
  __shared__ float keysS[32 * 256];   // 32 KB
  __shared__ float WqS[64 * 64];      // 16 KB (d-chunk x c-tile)
  const int t = threadIdx.x;
  const int h = blockIdx.x;           // 4
  const int c0 = blockIdx.y * 64;     // 32 tiles
#pragma unroll
  for (int it = 0; it < 32; it++) keysS[t + it * 256] = keysf_g[t + it * 256];
  const int n0 = (t >> 5) * 4;        // 8 groups x 4 n
  const int c2 = (t & 31) * 2;        // 32 groups x 2 c
  float acc[4][2] = {};
  for (int dc = 0; dc < 4; dc++) {    // d chunks of 64
    __syncthreads();
#pragma unroll
    for (int it = 0; it < 16; it++) {
      int i = t + it * 256;
      int r = i >> 6, c = i & 63;
      WqS[i] = Wq[(size_t)(h * 256 + dc * 64 + r) * 2048 + c0 + c];
    }
    __syncthreads();
    for (int d4 = 0; d4 < 16; d4++) {
      float4 kv[4];
#pragma unroll
      for (int i = 0; i < 4; i++)
        kv[i] = *(const float4*)&keysS[(n0 + i) * 256 + dc * 64 + d4 * 4];
#pragma unroll
      for (int dd = 0; dd < 4; dd++) {
        float2 w2 = *(const float2*)&WqS[(d4 * 4 + dd) * 64 + c2];
        float kvd[4] = {kv[0][dd], kv[1][dd], kv[2][dd], kv[3][dd]};
#pragma unroll
        for (int i = 0; i < 4; i++) {
          acc[i][0] = fmaf(kvd[i], w2.x, acc[i][0]);
          acc[i][1] = fmaf(kvd[i], w2.y, acc[i][1]);
        }
      }
    }
  }
#pragma unroll
  for (int i = 0; i < 4; i++) {
    u32 pk = (u32)f2bf(acc[i][0]) | ((u32)f2bf(acc[i][1]) << 16);
    *(u32*)&Kp[(size_t)(h * 32 + n0 + i) * 2048 + c0 + c2] = pk;
  }
}

// ---------- VWo build: VWoT[c, h*32+n] = sum_d vals[n,d] * Wo[c, h*256+d], bf16 out ----------
__global__ __launch_bounds__(256) void k_build_vwo(const float* __restrict__ Wo,
                                                   const float* __restrict__ valsf_g,
                                                   u16* __restrict__ VWoT) {
  __shared__ float valsS[32 * 256];   // 32 KB
  __shared__ float WoS[32 * 256];     // 32 KB (c-tile x d)
  const int t = threadIdx.x;
  const int c0 = blockIdx.x * 32;     // 64 tiles
#pragma unroll
  for (int it = 0; it < 32; it++) valsS[t + it * 256] = valsf_g[t + it * 256];
  const int c = t >> 3;               // 32
  const int n0 = (t & 7) * 4;         // 8 x 4 n
  for (int h = 0; h < 4; h++) {
    __syncthreads();
#pragma unroll
    for (int it = 0; it < 32; it++) {
      int i = t + it * 256;
      int r = i >> 8, d = i & 255;
      WoS[i] = Wo[(size_t)(c0 + r) * 1024 + h * 256 + d];
    }
    __syncthreads();
    float acc[4] = {};
    for (int d4 = 0; d4 < 64; d4++) {
      float4 w4 = *(const float4*)&WoS[c * 256 + d4 * 4];
#pragma unroll
      for (int i = 0; i < 4; i++) {
        float4 kv = *(const float4*)&valsS[(n0 + i) * 256 + d4 * 4];
        acc[i] = fmaf(w4.x, kv.x, acc[i]);
        acc[i] = fmaf(w4.y, kv.y, acc[i]);
        acc[i] = fmaf(w4.z, kv.z, acc[i]);
        acc[i] = fmaf(w4.w, kv.w, acc[i]);
      }
    }
    ushort4 o; o.x = f2bf(acc[0]); o.y = f2bf(acc[1]); o.z = f2bf(acc[2]); o.w = f2bf(acc[3]);
    *(ushort4*)&VWoT[(size_t)(c0 + c) * 128 + h * 32 + n0] = o;
  }
}

// ---------- generalized m97-style 128x128 bf16 NT GEMM with split-K ----------
// C[p][m][n] = sum_{k in split p} A[m][k] * B[n][k]
__global__ __launch_bounds__(256) void k_gemm_nt(const u16* __restrict__ A,
                                                 const u16* __restrict__ B,
                                                 float* __restrict__ C,
                                                 int N, int lda, int ldb, int kcount, int M) {
  __shared__ __align__(16) u16 As[128 * 32];
  __shared__ __align__(16) u16 Bs[128 * 32];
  const int t = threadIdx.x;
  const int w = t >> 6, l = t & 63;
  const int m0 = blockIdx.y * 128, n0 = blockIdx.x * 128;
  const int p = blockIdx.z;
  const int wm = (w >> 1) * 64, wn = (w & 1) * 64;
  const int c = l & 15, q = l >> 4;
  f32x4 acc[4][4] = {};
  const int rsrc = w * 16 + (l >> 2);
  const int kc = (l & 3) * 8;
  const u16* Ab = A + (size_t)(m0 + rsrc) * lda + (size_t)p * kcount + kc;
  const u16* Bb = B + (size_t)(n0 + rsrc) * ldb + (size_t)p * kcount + kc;
  C += (size_t)p * M * N;
  u16* AsW = &As[w * 512];
  u16* BsW = &Bs[w * 512];
  for (int kt = 0; kt < kcount; kt += 32) {
    gld_lds16(Ab + kt, AsW);
    gld_lds16(Ab + (size_t)64 * lda + kt, AsW + 2048);
    gld_lds16(Bb + kt, BsW);
    gld_lds16(Bb + (size_t)64 * ldb + kt, BsW + 2048);
    __syncthreads();
    bf16x8 af[4], bfr[4];
#pragma unroll
    for (int i = 0; i < 4; i++)
      af[i] = __builtin_bit_cast(bf16x8, *(const uint4*)&As[(wm + i * 16 + c) * 32 + q * 8]);
#pragma unroll
    for (int i = 0; i < 4; i++)
      bfr[i] = __builtin_bit_cast(bf16x8, *(const uint4*)&Bs[(wn + i * 16 + c) * 32 + q * 8]);
#pragma unroll
    for (int mi = 0; mi < 4; mi++)
#pragma unroll
      for (int ni = 0; ni < 4; ni++)
        acc[mi][ni] = __builtin_amdgcn_mfma_f32_16x16x32_bf16(af[mi], bfr[ni], acc[mi][ni], 0, 0, 0);
    __syncthreads();
  }
#pragma unroll
  for (int mi = 0; mi < 4; mi++)
#pragma unroll
    for (int ni = 0; ni < 4; ni++)
#pragma unroll
      for (int r = 0; r < 4; r++) {
        int row = m0 + wm + mi * 16 + q * 4 + r;
        int col = n0 + wn + ni * 16 + c;
        C[(size_t)row * N + col] = acc[mi][ni][r];
      }
}

// ---------- softmax over split-K score partials -> P bf16 ----------
__global__ __launch_bounds__(256) void k_soft(const float* __restrict__ Sp,
                                              const float* __restrict__ bias,
                                              const float* __restrict__ temp,
                                              u16* __restrict__ P) {
  __shared__ float biasS[32];
  __shared__ float tS[4];
  const int t = threadIdx.x;
  if (t < 32) biasS[t] = bias[t];
  if (t < 4) tS[t] = temp[t];
  __syncthreads();
  const int w = t >> 6, l = t & 63;
  const int row = blockIdx.x * 4 + w;
  const size_t base = (size_t)row * 128;
  const size_t SPN = (size_t)16384 * 128;
  float s1 = Sp[base + l] + Sp[SPN + base + l] + Sp[2 * SPN + base + l] + Sp[3 * SPN + base + l];
  float s2 = Sp[base + 64 + l] + Sp[SPN + base + 64 + l] + Sp[2 * SPN + base + 64 + l] + Sp[3 * SPN + base + 64 + l];
  const int n = l & 31;
  float v1 = fmaf(s1, tS[l >> 5] * 0.0625f, biasS[n]);
  float v2 = fmaf(s2, tS[2 + (l >> 5)] * 0.0625f, biasS[n]);
  float m1 = v1, m2 = v2;
#pragma unroll
  for (int mk = 1; mk <= 16; mk <<= 1) { m1 = fmaxf(m1, __shfl_xor(m1, mk)); m2 = fmaxf(m2, __shfl_xor(m2, mk)); }
  float e1 = __expf(v1 - m1), e2 = __expf(v2 - m2);
  float q1 = e1, q2 = e2;
#pragma unroll
  for (int mk = 1; mk <= 16; mk <<= 1) { q1 += __shfl_xor(q1, mk); q2 += __shfl_xor(q2, mk); }
  P[base + l] = f2bf(e1 / q1);
  P[base + 64 + l] = f2bf(e2 / q2);
}

// ---------- launch ----------
extern "C" void kernel_launch(void* const* d_in, const int* in_sizes, int n_in,
                              void* d_out, int out_size, void* d_ws, size_t ws_size,
                              hipStream_t stream) {
  const float* hidden = (const float*)d_in[0];
  const float* beliefs = (const float*)d_in[1];
  const void* amask = d_in[2];
  const float* goals = (const float*)d_in[3];
  const float* prio = (const float*)d_in[4];
  const float* Wq = (const float*)d_in[5];
  const float* Wo = (const float*)d_in[6];
  const float* logt = (const float*)d_in[7];
  float* out = (float*)d_out;

  char* ws = (char*)d_ws;
  size_t off = 0;
  auto alloc = [&](size_t bytes) { char* p = ws + off; off = (off + bytes + 255) & ~(size_t)255; return p; };
  u16* hb      = (u16*)alloc(67108864);    // hidden bf16
  float* Sp    = (float*)alloc(33554432);  // 4 split-K score partials [16384*128] f32
  u16* P       = (u16*)alloc(4194304);     // attn weights bf16 [16384*128]
  u16* kp      = (u16*)alloc(524288);      // K' [128 x 2048] bf16
  u16* vwot    = (u16*)alloc(524288);      // VWo^T [2048 x 128] bf16
  float* partial = (float*)alloc(524288);
  float* meanq = (float*)alloc(8192);
  float* rq    = (float*)alloc(1024);
  u64* keys    = (u64*)alloc(524288);
  u64* cands   = (u64*)alloc(16384);
  int* topkidx = (int*)alloc(128);
  float* keysf = (float*)alloc(32768);
  float* valsf = (float*)alloc(32768);
  float* biasv = (float*)alloc(128);
  float* tempv = (float*)alloc(16);
  int* flag    = (int*)alloc(16);

  hipMemsetAsync(rq, 0, 1024, stream);
  k_detect<<<1, 64, 0, stream>>>((const u32*)amask, flag);
  k_conv_mean<<<dim3(2, 64), 256, 0, stream>>>((const float4*)hidden, (ushort4*)hb, (float4*)partial);
  k_mean<<<8, 256, 0, stream>>>(partial, meanq);
  k_rq<<<256, 256, 0, stream>>>(Wq, meanq, rq);
  k_rough<<<16384, 256, 0, stream>>>(beliefs, amask, flag, rq, keys);
  k_topk<<<64, 256, 0, stream>>>(keys, 1024, cands, nullptr);
  k_topk<<<1, 256, 0, stream>>>(cands, 2048, nullptr, topkidx);
  k_prep<<<1, 256, 0, stream>>>(beliefs, goals, prio, logt, topkidx, keysf, valsf, biasv, tempv);
  k_build_kp<<<dim3(4, 32), 256, 0, stream>>>(Wq, keysf, kp);
  k_build_vwo<<<64, 256, 0, stream>>>(Wo, valsf, vwot);
  // scores: S[16384,128] = hb[16384,2048] @ kp^T, split-K=4 (K=512 each)
  k_gemm_nt<<<dim3(1, 128, 4), 256, 0, stream>>>(hb, kp, Sp, 128, 2048, 2048, 512, 16384);
  k_soft<<<4096, 256, 0, stream>>>(Sp, biasv, tempv, P);
  // out: [16384,2048] = P[16384,128] @ vwot^T (K=128)
  k_gemm_nt<<<dim3(16, 128, 1), 256, 0, stream>>>(P, vwot, out, 2048, 128, 128, 128, 16384);
}

// Round 3
// 538.179 us; speedup vs baseline: 1.3405x; 1.0279x over previous
//
#include <hip/hip_runtime.h>

typedef unsigned int u32;
typedef unsigned short u16;
typedef unsigned long long u64;

typedef __bf16 bf16x8 __attribute__((ext_vector_type(8)));
typedef float f32x4 __attribute__((ext_vector_type(4)));

#define DEV __device__ __forceinline__

// ---------- helpers ----------
DEV u16 f2bf(float f) {            // RNE float -> bf16
  u32 u = __float_as_uint(f);
  u += 0x7fffu + ((u >> 16) & 1u);
  return (u16)(u >> 16);
}
DEV float bf2f(u16 u) { return __uint_as_float((u32)u << 16); }

DEV void gld_lds16(const void* g, void* l) {
  __builtin_amdgcn_global_load_lds((const __attribute__((address_space(1))) u32*)g,
                                   (__attribute__((address_space(3))) u32*)l, 16, 0, 0);
}

// monotone (value, lower-index-wins) packed sort key
DEV u64 packkey(float f, u32 idx) {
  u32 u = __float_as_uint(f);
  u = (u & 0x80000000u) ? ~u : (u | 0x80000000u);
  return ((u64)u << 32) | (u32)(~idx);
}

// ---------- hidden -> bf16 + column partial sums (float4, 512 blocks) ----------
__global__ __launch_bounds__(256) void k_conv_mean(const float4* __restrict__ hidden4,
                                                   ushort4* __restrict__ hb4,
                                                   float4* __restrict__ partial4) {
  const int c4 = blockIdx.x * 256 + threadIdx.x;   // 0..511
  const int r0 = blockIdx.y * 64;                  // 256 row-chunks
  float4 s = {0.f, 0.f, 0.f, 0.f};
  for (int r = 0; r < 64; r++) {
    float4 v = hidden4[(size_t)(r0 + r) * 512 + c4];
    ushort4 o; o.x = f2bf(v.x); o.y = f2bf(v.y); o.z = f2bf(v.z); o.w = f2bf(v.w);
    hb4[(size_t)(r0 + r) * 512 + c4] = o;
    s.x += v.x; s.y += v.y; s.z += v.z; s.w += v.w;
  }
  partial4[blockIdx.y * 512 + c4] = s;
}

// reduce 256 chunks -> mean (128 blocks, 16 cols each, 16-way split per col)
__global__ __launch_bounds__(256) void k_mean(const float* __restrict__ partial,
                                              float* __restrict__ mean) {
  __shared__ float red[256];
  const int t = threadIdx.x;
  const int c = t & 15, s = t >> 4;
  const int col = blockIdx.x * 16 + c;
  float acc = 0.f;
  for (int ch = s; ch < 256; ch += 16) acc += partial[ch * 2048 + col];
  red[t] = acc;
  __syncthreads();
  for (int st = 8; st > 0; st >>= 1) {
    if (s < st) red[t] += red[t + st * 16];
    __syncthreads();
  }
  if (s == 0) mean[col] = red[c] * (1.0f / 16384.0f);
}

// rough_query[d] = 0.25 * sum_h dot(Wq[h*256+d, :], mean)  — one wave per row
__global__ __launch_bounds__(256) void k_rq(const float* __restrict__ Wq,
                                            const float* __restrict__ mean,
                                            float* __restrict__ rq) {
  const int w = threadIdx.x >> 6, l = threadIdx.x & 63;
  const int row = blockIdx.x * 4 + w;      // 1024 rows
  float s = 0.f;
#pragma unroll
  for (int j = 0; j < 32; j++)
    s = fmaf(Wq[(size_t)row * 2048 + j * 64 + l], mean[j * 64 + l], s);
  for (int mk = 1; mk < 64; mk <<= 1) s += __shfl_xor(s, mk);
  if (l == 0) atomicAdd(&rq[row & 255], 0.25f * s);
}

// ---------- rough scores (one wave per belief; mask layout sniffed inline) ----------
__global__ __launch_bounds__(256) void k_rough(const float* __restrict__ beliefs,
                                               const void* __restrict__ amask,
                                               const float* __restrict__ rq,
                                               u64* __restrict__ keys) {
  const int t = threadIdx.x, w = t >> 6, l = t & 63;
  const int n = blockIdx.x * 4 + w;
  // layout sniff: int32 words of 0/1 vs packed bytes (first 64 words, L2-hot)
  u32 mv = ((const u32*)amask)[l];
  bool isInt = (__ballot(mv > 1u) == 0ull);
  float4 b = *(const float4*)(beliefs + (size_t)n * 256 + l * 4);
  float4 qv = *(const float4*)(rq + l * 4);
  float dot = b.x * qv.x + b.y * qv.y + b.z * qv.z + b.w * qv.w;
  float ss = b.x * b.x + b.y * b.y + b.z * b.z + b.w * b.w;
  for (int mk = 1; mk < 64; mk <<= 1) { dot += __shfl_xor(dot, mk); ss += __shfl_xor(ss, mk); }
  if (l == 0) {
    bool act = isInt ? (((const int*)amask)[n] != 0)
                     : (((const unsigned char*)amask)[n] != 0);
    float score = act ? dot / fmaxf(sqrtf(ss), 1e-8f) : -1e30f;
    keys[n] = packkey(score, (u32)n);
  }
}

// ---------- exact top-32, hierarchical argmax over packed keys ----------
__global__ __launch_bounds__(256) void k_topk(const u64* __restrict__ in, int cnt,
                                              u64* __restrict__ outk, int* __restrict__ outi) {
  __shared__ u64 buf[2048];
  __shared__ u64 wmaxS[4];
  const int t = threadIdx.x;
  const int slots = cnt >> 8;
  const u64* src = in + (size_t)blockIdx.x * cnt;
  for (int i = 0; i < slots; i++) buf[t + i * 256] = src[t + i * 256];
  __syncthreads();
  const int l = t & 63, w = t >> 6;
  for (int r = 0; r < 32; r++) {
    u64 m = 0;
    for (int i = 0; i < slots; i++) { u64 v = buf[t + i * 256]; m = v > m ? v : m; }
    for (int mk = 1; mk < 64; mk <<= 1) { u64 o = __shfl_xor(m, mk); m = o > m ? o : m; }
    if (l == 0) wmaxS[w] = m;
    __syncthreads();
    u64 a = wmaxS[0] > wmaxS[1] ? wmaxS[0] : wmaxS[1];
    u64 b = wmaxS[2] > wmaxS[3] ? wmaxS[2] : wmaxS[3];
    u64 win = a > b ? a : b;
    for (int i = 0; i < slots; i++) if (buf[t + i * 256] == win) buf[t + i * 256] = 0ull;
    if (t == 0) {
      if (outk) outk[blockIdx.x * 32 + r] = win;
      if (outi) outi[r] = (int)(~(u32)(win & 0xffffffffull));
    }
    __syncthreads();
  }
}

// ---------- gather + keys(f32)/values(f32)/goal-bias/temperature ----------
__global__ __launch_bounds__(256) void k_prep(const float* __restrict__ beliefs,
                                              const float* __restrict__ goals,
                                              const float* __restrict__ prio,
                                              const float* __restrict__ logt,
                                              const int* __restrict__ topk,
                                              float* __restrict__ keysf_g,
                                              float* __restrict__ valsf_g,
                                              float* __restrict__ biasO, float* __restrict__ tempO) {
  __shared__ float keysf[32 * 256];
  __shared__ float gradS[16];
  const int t = threadIdx.x, w = t >> 6, l = t & 63;
  for (int g = w * 4; g < w * 4 + 4; g++) {
    float4 v = *(const float4*)(goals + g * 256 + l * 4);
    float ss = v.x * v.x + v.y * v.y + v.z * v.z + v.w * v.w;
    for (int mk = 1; mk < 64; mk <<= 1) ss += __shfl_xor(ss, mk);
    if (l == 0) gradS[g] = fmaxf(sqrtf(ss), 1e-8f);
  }
  for (int kk = w * 8; kk < w * 8 + 8; kk++) {
    int idx = topk[kk];
    float4 v = *(const float4*)(beliefs + (size_t)idx * 256 + l * 4);
    float ss = v.x * v.x + v.y * v.y + v.z * v.z + v.w * v.w;
    for (int mk = 1; mk < 64; mk <<= 1) ss += __shfl_xor(ss, mk);
    float rr = 1.0f / fmaxf(sqrtf(ss), 1e-8f);
    float4 kv; kv.x = v.x * rr; kv.y = v.y * rr; kv.z = v.z * rr; kv.w = v.w * rr;
    *(float4*)&keysf[kk * 256 + l * 4] = kv;
    *(float4*)&keysf_g[kk * 256 + l * 4] = kv;
    *(float4*)&valsf_g[kk * 256 + l * 4] = v;
  }
  __syncthreads();
  for (int kk = w * 8; kk < w * 8 + 8; kk++) {
    float4 kv = *(const float4*)&keysf[kk * 256 + l * 4];
    float best = -1e30f;
    for (int g = 0; g < 16; g++) {
      float4 gv = *(const float4*)(goals + g * 256 + l * 4);
      float d = kv.x * gv.x + kv.y * gv.y + kv.z * gv.z + kv.w * gv.w;
      for (int mk = 1; mk < 64; mk <<= 1) d += __shfl_xor(d, mk);
      float sim = d / gradS[g] * prio[g];
      best = fmaxf(best, sim);
    }
    if (l == 0) biasO[kk] = best;
  }
  if (t < 4) tempO[t] = fmaxf(__expf(logt[t]), 0.1f);
}

// ---------- K' build: Kp[h*32+n, c] = sum_d keys[n,d] * Wq[h*256+d, c], bf16 out ----------
__global__ __launch_bounds__(256) void k_build_kp(const float* __restrict__ Wq,
                                                  const float* __restrict__ keysf_g,
                                                  u16* __restrict__ Kp) {
  __shared__ float keysS[32 * 256];   // 32 KB
  __shared__ float WqS[64 * 64];      // 16 KB
  const int t = threadIdx.x;
  const int h = blockIdx.x;           // 4
  const int c0 = blockIdx.y * 64;     // 32 tiles
#pragma unroll
  for (int it = 0; it < 32; it++) keysS[t + it * 256] = keysf_g[t + it * 256];
  const int n0 = (t >> 5) * 4;
  const int c2 = (t & 31) * 2;
  float acc[4][2] = {};
  for (int dc = 0; dc < 4; dc++) {
    __syncthreads();
#pragma unroll
    for (int it = 0; it < 16; it++) {
      int i = t + it * 256;
      int r = i >> 6, c = i & 63;
      WqS[i] = Wq[(size_t)(h * 256 + dc * 64 + r) * 2048 + c0 + c];
    }
    __syncthreads();
    for (int d4 = 0; d4 < 16; d4++) {
      float4 kv[4];
#pragma unroll
      for (int i = 0; i < 4; i++)
        kv[i] = *(const float4*)&keysS[(n0 + i) * 256 + dc * 64 + d4 * 4];
#pragma unroll
      for (int dd = 0; dd < 4; dd++) {
        float2 w2 = *(const float2*)&WqS[(d4 * 4 + dd) * 64 + c2];
        float kvd[4] = {kv[0][dd], kv[1][dd], kv[2][dd], kv[3][dd]};
#pragma unroll
        for (int i = 0; i < 4; i++) {
          acc[i][0] = fmaf(kvd[i], w2.x, acc[i][0]);
          acc[i][1] = fmaf(kvd[i], w2.y, acc[i][1]);
        }
      }
    }
  }
#pragma unroll
  for (int i = 0; i < 4; i++) {
    u32 pk = (u32)f2bf(acc[i][0]) | ((u32)f2bf(acc[i][1]) << 16);
    *(u32*)&Kp[(size_t)(h * 32 + n0 + i) * 2048 + c0 + c2] = pk;
  }
}

// ---------- VWo build: VWoT[c, h*32+n] = sum_d vals[n,d] * Wo[c, h*256+d], bf16 out ----------
__global__ __launch_bounds__(256) void k_build_vwo(const float* __restrict__ Wo,
                                                   const float* __restrict__ valsf_g,
                                                   u16* __restrict__ VWoT) {
  __shared__ float valsS[32 * 256];
  __shared__ float WoS[32 * 256];
  const int t = threadIdx.x;
  const int c0 = blockIdx.x * 32;     // 64 tiles
#pragma unroll
  for (int it = 0; it < 32; it++) valsS[t + it * 256] = valsf_g[t + it * 256];
  const int c = t >> 3;
  const int n0 = (t & 7) * 4;
  for (int h = 0; h < 4; h++) {
    __syncthreads();
#pragma unroll
    for (int it = 0; it < 32; it++) {
      int i = t + it * 256;
      int r = i >> 8, d = i & 255;
      WoS[i] = Wo[(size_t)(c0 + r) * 1024 + h * 256 + d];
    }
    __syncthreads();
    float acc[4] = {};
    for (int d4 = 0; d4 < 64; d4++) {
      float4 w4 = *(const float4*)&WoS[c * 256 + d4 * 4];
#pragma unroll
      for (int i = 0; i < 4; i++) {
        float4 kv = *(const float4*)&valsS[(n0 + i) * 256 + d4 * 4];
        acc[i] = fmaf(w4.x, kv.x, acc[i]);
        acc[i] = fmaf(w4.y, kv.y, acc[i]);
        acc[i] = fmaf(w4.z, kv.z, acc[i]);
        acc[i] = fmaf(w4.w, kv.w, acc[i]);
      }
    }
    ushort4 o; o.x = f2bf(acc[0]); o.y = f2bf(acc[1]); o.z = f2bf(acc[2]); o.w = f2bf(acc[3]);
    *(ushort4*)&VWoT[(size_t)(c0 + c) * 128 + h * 32 + n0] = o;
  }
}

// ---------- generalized m97-style 128x128 bf16 NT GEMM with split-K ----------
template <typename OutT>
__global__ __launch_bounds__(256) void k_gemm_nt(const u16* __restrict__ A,
                                                 const u16* __restrict__ B,
                                                 OutT* __restrict__ C,
                                                 int N, int lda, int ldb, int kcount, int M) {
  __shared__ __align__(16) u16 As[128 * 32];
  __shared__ __align__(16) u16 Bs[128 * 32];
  const int t = threadIdx.x;
  const int w = t >> 6, l = t & 63;
  const int m0 = blockIdx.y * 128, n0 = blockIdx.x * 128;
  const int p = blockIdx.z;
  const int wm = (w >> 1) * 64, wn = (w & 1) * 64;
  const int c = l & 15, q = l >> 4;
  f32x4 acc[4][4] = {};
  const int rsrc = w * 16 + (l >> 2);
  const int kc = (l & 3) * 8;
  const u16* Ab = A + (size_t)(m0 + rsrc) * lda + (size_t)p * kcount + kc;
  const u16* Bb = B + (size_t)(n0 + rsrc) * ldb + (size_t)p * kcount + kc;
  C += (size_t)p * M * N;
  u16* AsW = &As[w * 512];
  u16* BsW = &Bs[w * 512];
  for (int kt = 0; kt < kcount; kt += 32) {
    gld_lds16(Ab + kt, AsW);
    gld_lds16(Ab + (size_t)64 * lda + kt, AsW + 2048);
    gld_lds16(Bb + kt, BsW);
    gld_lds16(Bb + (size_t)64 * ldb + kt, BsW + 2048);
    __syncthreads();
    bf16x8 af[4], bfr[4];
#pragma unroll
    for (int i = 0; i < 4; i++)
      af[i] = __builtin_bit_cast(bf16x8, *(const uint4*)&As[(wm + i * 16 + c) * 32 + q * 8]);
#pragma unroll
    for (int i = 0; i < 4; i++)
      bfr[i] = __builtin_bit_cast(bf16x8, *(const uint4*)&Bs[(wn + i * 16 + c) * 32 + q * 8]);
#pragma unroll
    for (int mi = 0; mi < 4; mi++)
#pragma unroll
      for (int ni = 0; ni < 4; ni++)
        acc[mi][ni] = __builtin_amdgcn_mfma_f32_16x16x32_bf16(af[mi], bfr[ni], acc[mi][ni], 0, 0, 0);
    __syncthreads();
  }
#pragma unroll
  for (int mi = 0; mi < 4; mi++)
#pragma unroll
    for (int ni = 0; ni < 4; ni++)
#pragma unroll
      for (int r = 0; r < 4; r++) {
        int row = m0 + wm + mi * 16 + q * 4 + r;
        int col = n0 + wn + ni * 16 + c;
        float v = acc[mi][ni][r];
        if constexpr (sizeof(OutT) == 2) C[(size_t)row * N + col] = (OutT)f2bf(v);
        else                             C[(size_t)row * N + col] = v;
      }
}

// ---------- softmax over split-K bf16 score partials -> P bf16 ----------
__global__ __launch_bounds__(256) void k_soft(const u16* __restrict__ Sp,
                                              const float* __restrict__ bias,
                                              const float* __restrict__ temp,
                                              u16* __restrict__ P) {
  __shared__ float biasS[32];
  __shared__ float tS[4];
  const int t = threadIdx.x;
  if (t < 32) biasS[t] = bias[t];
  if (t < 4) tS[t] = temp[t];
  __syncthreads();
  const int w = t >> 6, l = t & 63;
  const int row = blockIdx.x * 4 + w;
  const size_t base = (size_t)row * 128;
  const size_t SPN = (size_t)16384 * 128;
  float s1 = bf2f(Sp[base + l]) + bf2f(Sp[SPN + base + l])
           + bf2f(Sp[2 * SPN + base + l]) + bf2f(Sp[3 * SPN + base + l]);
  float s2 = bf2f(Sp[base + 64 + l]) + bf2f(Sp[SPN + base + 64 + l])
           + bf2f(Sp[2 * SPN + base + 64 + l]) + bf2f(Sp[3 * SPN + base + 64 + l]);
  const int n = l & 31;
  float v1 = fmaf(s1, tS[l >> 5] * 0.0625f, biasS[n]);
  float v2 = fmaf(s2, tS[2 + (l >> 5)] * 0.0625f, biasS[n]);
  float m1 = v1, m2 = v2;
#pragma unroll
  for (int mk = 1; mk <= 16; mk <<= 1) { m1 = fmaxf(m1, __shfl_xor(m1, mk)); m2 = fmaxf(m2, __shfl_xor(m2, mk)); }
  float e1 = __expf(v1 - m1), e2 = __expf(v2 - m2);
  float q1 = e1, q2 = e2;
#pragma unroll
  for (int mk = 1; mk <= 16; mk <<= 1) { q1 += __shfl_xor(q1, mk); q2 += __shfl_xor(q2, mk); }
  P[base + l] = f2bf(e1 / q1);
  P[base + 64 + l] = f2bf(e2 / q2);
}

// ---------- launch ----------
extern "C" void kernel_launch(void* const* d_in, const int* in_sizes, int n_in,
                              void* d_out, int out_size, void* d_ws, size_t ws_size,
                              hipStream_t stream) {
  const float* hidden = (const float*)d_in[0];
  const float* beliefs = (const float*)d_in[1];
  const void* amask = d_in[2];
  const float* goals = (const float*)d_in[3];
  const float* prio = (const float*)d_in[4];
  const float* Wq = (const float*)d_in[5];
  const float* Wo = (const float*)d_in[6];
  const float* logt = (const float*)d_in[7];
  float* out = (float*)d_out;

  char* ws = (char*)d_ws;
  size_t off = 0;
  auto alloc = [&](size_t bytes) { char* p = ws + off; off = (off + bytes + 255) & ~(size_t)255; return p; };
  u16* hb      = (u16*)alloc(67108864);    // hidden bf16
  u16* Sp      = (u16*)alloc(16777216);    // 4 split-K score partials [16384*128] bf16
  u16* P       = (u16*)alloc(4194304);     // attn weights bf16 [16384*128]
  u16* kp      = (u16*)alloc(524288);      // K' [128 x 2048] bf16
  u16* vwot    = (u16*)alloc(524288);      // VWo^T [2048 x 128] bf16
  float* partial = (float*)alloc(2097152); // 256 chunks x 2048 cols
  float* meanq = (float*)alloc(8192);
  float* rq    = (float*)alloc(1024);
  u64* keys    = (u64*)alloc(524288);
  u64* cands   = (u64*)alloc(16384);
  int* topkidx = (int*)alloc(128);
  float* keysf = (float*)alloc(32768);
  float* valsf = (float*)alloc(32768);
  float* biasv = (float*)alloc(128);
  float* tempv = (float*)alloc(16);

  hipMemsetAsync(rq, 0, 1024, stream);
  k_conv_mean<<<dim3(2, 256), 256, 0, stream>>>((const float4*)hidden, (ushort4*)hb, (float4*)partial);
  k_mean<<<128, 256, 0, stream>>>(partial, meanq);
  k_rq<<<256, 256, 0, stream>>>(Wq, meanq, rq);
  k_rough<<<16384, 256, 0, stream>>>(beliefs, amask, rq, keys);
  k_topk<<<64, 256, 0, stream>>>(keys, 1024, cands, nullptr);
  k_topk<<<1, 256, 0, stream>>>(cands, 2048, nullptr, topkidx);
  k_prep<<<1, 256, 0, stream>>>(beliefs, goals, prio, logt, topkidx, keysf, valsf, biasv, tempv);
  k_build_kp<<<dim3(4, 32), 256, 0, stream>>>(Wq, keysf, kp);
  k_build_vwo<<<64, 256, 0, stream>>>(Wo, valsf, vwot);
  // scores: S[16384,128] = hb[16384,2048] @ kp^T, split-K=4 (K=512 each), bf16 partials
  k_gemm_nt<u16><<<dim3(1, 128, 4), 256, 0, stream>>>(hb, kp, Sp, 128, 2048, 2048, 512, 16384);
  k_soft<<<4096, 256, 0, stream>>>(Sp, biasv, tempv, P);
  // out: [16384,2048] = P[16384,128] @ vwot^T (K=128)
  k_gemm_nt<float><<<dim3(16, 128, 1), 256, 0, stream>>>(P, vwot, out, 2048, 128, 128, 128, 16384);
}